// Round 23
// baseline (440.297 us; speedup 1.0000x reference)
//
#include <hip/hip_runtime.h>
#include <hip/hip_bf16.h>
#include <math.h>

typedef __bf16 bf16x8 __attribute__((ext_vector_type(8)));
typedef float  f32x4  __attribute__((ext_vector_type(4)));

#define MFMA16 __builtin_amdgcn_mfma_f32_16x16x32_bf16

__device__ __forceinline__ float silu_f(float v) {
    return v * __builtin_amdgcn_rcpf(1.0f + __expf(-v));
}

// LDS weight layout: Wt[j][k], bf16, 16B-chunk XOR swizzle:
// phys = j*K + (((k>>3) ^ (j&7))<<3) + (k&7)  -> ds_read_b128, 2-way max.

// ---- detector: is edge_index stored as int64 (odd words all zero)? ---------
__global__ void k_detect(const int* __restrict__ ei, int* __restrict__ flag) {
    __shared__ int red[256];
    int v = 0;
#pragma unroll
    for (int j = 0; j < 4; ++j) v |= ei[2 * (threadIdx.x * 4 + j) + 1];
    red[threadIdx.x] = v;
    __syncthreads();
    for (int s = 128; s > 0; s >>= 1) {
        if (threadIdx.x < s) red[threadIdx.x] |= red[threadIdx.x + s];
        __syncthreads();
    }
    if (threadIdx.x == 0) *flag = (red[0] == 0) ? 1 : 0;
}

// ---- CSR build --------------------------------------------------------------
__global__ __launch_bounds__(256) void k_hist(
    const int* __restrict__ ei, const int* __restrict__ flag,
    int* __restrict__ counts, int E)
{
    int e = blockIdx.x * 256 + threadIdx.x;
    if (e >= E) return;
    const int is64 = *flag;
    int r = is64 ? ei[2 * E + 2 * e] : ei[E + e];
    atomicAdd(&counts[r], 1);
}

// single-block hierarchical scan: counts -> offs (exclusive) + cursor copy
__global__ __launch_bounds__(1024) void k_scanall(
    const int* __restrict__ counts, int* __restrict__ offs,
    int* __restrict__ cursor, int N)
{
    __shared__ int buf[1024];
    const int t = threadIdx.x;
    const int nper = (N + 1023) / 1024;
    const int base = t * nper;
    int sum = 0;
    for (int i = 0; i < nper; ++i) {
        const int idx = base + i;
        if (idx < N) sum += counts[idx];
    }
    buf[t] = sum;
    __syncthreads();
    for (int d = 1; d < 1024; d <<= 1) {
        int v = buf[t];
        int w = (t >= d) ? buf[t - d] : 0;
        __syncthreads();
        buf[t] = v + w;
        __syncthreads();
    }
    int run = buf[t] - sum;          // exclusive prefix of this thread's range
    for (int i = 0; i < nper; ++i) {
        const int idx = base + i;
        if (idx < N) {
            offs[idx]   = run;
            cursor[idx] = run;
            run += counts[idx];
        }
    }
}

// scatter + per-edge distance precompute (kills pos-gather chains downstream)
__global__ __launch_bounds__(256) void k_scatter(
    const int* __restrict__ ei, const int* __restrict__ flag,
    const float* __restrict__ pos, int* __restrict__ cursor,
    int* __restrict__ csr_s, int* __restrict__ csr_r,
    float* __restrict__ dist, int E)
{
    int e = blockIdx.x * 256 + threadIdx.x;
    if (e >= E) return;
    const int is64 = *flag;
    int s, r;
    if (is64) { s = ei[2 * e]; r = ei[2 * E + 2 * e]; }
    else      { s = ei[e];     r = ei[E + e];         }
    float dx = pos[3 * s]     - pos[3 * r];
    float dy = pos[3 * s + 1] - pos[3 * r + 1];
    float dz = pos[3 * s + 2] - pos[3 * r + 2];
    float d  = sqrtf(dx * dx + dy * dy + dz * dz);
    int slot = atomicAdd(&cursor[r], 1);
    csr_s[slot] = s;
    csr_r[slot] = r;
    dist[slot]  = d;
}

// ---- phase 1: AB[n][0:128]=bf16(x@W1a + b1), AB[n][128:256]=bf16(x@W1b) ----
__global__ __launch_bounds__(256) void k_node1(
    const float* __restrict__ x, const float* __restrict__ W1,
    const float* __restrict__ b1, __bf16* __restrict__ AB, int N, int ngroups)
{
    __shared__ __bf16 wt[256 * 128];
    for (int idx = threadIdx.x; idx < 256 * 128; idx += 256) {
        int j = idx & 255, k = idx >> 8;
        float w = (j < 128) ? W1[(k << 7) + j] : W1[((k + 128) << 7) + (j - 128)];
        wt[(j << 7) + ((((k >> 3) ^ (j & 7))) << 3) + (k & 7)] = (__bf16)w;
    }
    __syncthreads();

    const int lane = threadIdx.x & 63;
    const int row  = lane & 15;
    const int kq   = lane >> 4;

    for (int g = blockIdx.x; g < ngroups; g += gridDim.x) {
        const int row0 = g * 64 + (threadIdx.x >> 6) * 16;
        int m = row0 + row; if (m >= N) m = N - 1;
        const float* xr = x + (size_t)m * 128;

        bf16x8 afr[4];
#pragma unroll
        for (int c = 0; c < 4; ++c) {
            const int k0 = c * 32 + kq * 8;
            float4 a0 = *(const float4*)(xr + k0);
            float4 a1 = *(const float4*)(xr + k0 + 4);
            bf16x8 af;
            af[0]=(__bf16)a0.x; af[1]=(__bf16)a0.y; af[2]=(__bf16)a0.z; af[3]=(__bf16)a0.w;
            af[4]=(__bf16)a1.x; af[5]=(__bf16)a1.y; af[6]=(__bf16)a1.z; af[7]=(__bf16)a1.w;
            afr[c] = af;
        }

        f32x4 acc[16] = {};
#pragma unroll
        for (int t = 0; t < 16; ++t) {
            const int j  = t * 16 + row;
            const int jb = j & 7;
            const __bf16* base = wt + (j << 7);
#pragma unroll
            for (int c = 0; c < 4; ++c) {
                const int kb = c * 4 + kq;
                bf16x8 b = *(const bf16x8*)(base + ((kb ^ jb) << 3));
                acc[t] = MFMA16(afr[c], b, acc[t], 0, 0, 0);
            }
        }

#pragma unroll
        for (int t = 0; t < 16; ++t) {
            const int col = t * 16 + row;
            const float bb = (col < 128) ? b1[col] : 0.0f;
#pragma unroll
            for (int q = 0; q < 4; ++q) {
                const int gr = row0 + kq * 4 + q;
                if (gr < N) AB[(size_t)gr * 256 + col] = (__bf16)(acc[t][q] + bb);
            }
        }
    }
}

// ---- FUSED edge v11 (k_edge_p3): wave-pair per RECEIVER-PAIR window --------
// Proven config (r21): 68 VGPR, 168 us. Combined contiguous pair window,
// k-half split first layer via double-buffered padded LDS h-tile, prefetch.
__global__ __launch_bounds__(256) void k_edge_p3(
    const __bf16* __restrict__ AB, const int* __restrict__ csr_s,
    const float* __restrict__ dist, const int* __restrict__ offs,
    const int* __restrict__ counts, const float* __restrict__ W2,
    const float* __restrict__ b2, const float* __restrict__ w3,
    float* __restrict__ aggr, int N)
{
    __shared__ __bf16 wt[128 * 128];          // 32 KB W2^T swizzled
    __shared__ float  w3s[128];
    __shared__ float  b2s[128];
    __shared__ __bf16 bsl[2][2][128];         // [pair-slot][rcv-of-pair] B-row
    __shared__ __bf16 hd[2][2][16 * 136];     // [pair-slot][buf] padded h-tile
    for (int idx = threadIdx.x; idx < 128 * 128; idx += 256) {
        int j = idx & 127, k = idx >> 7;
        wt[(j << 7) + ((((k >> 3) ^ (j & 7))) << 3) + (k & 7)] = (__bf16)W2[(k << 7) + j];
    }
    for (int i = threadIdx.x; i < 128; i += 256) { w3s[i] = w3[i]; b2s[i] = b2[i]; }
    __syncthreads();

    const int lane = threadIdx.x & 63;
    const int row  = lane & 15;
    const int kq   = lane >> 4;
    const int wid  = threadIdx.x >> 6;
    const int ps   = wid >> 1;
    const int hf   = wid & 1;
    const int nquad = (N + 3) >> 2;

    for (int Q = blockIdx.x; Q < nquad; Q += gridDim.x) {
        const int r0 = 4 * Q + 2 * ps;
        const int r1 = r0 + 1;
        const bool v0 = (r0 < N), v1 = (r1 < N);
        const int w0   = v0 ? offs[r0]   : 0;
        const int deg0 = v0 ? counts[r0] : 0;
        const int deg1 = v1 ? counts[r1] : 0;
        const int degsum = deg0 + deg1;
        const int o0  = 4 * Q + 2 * (ps ^ 1);
        const int od0 = (o0 < N)     ? counts[o0]     : 0;
        const int od1 = (o0 + 1 < N) ? counts[o0 + 1] : 0;
        const int osum = od0 + od1;
        const int msum = degsum > osum ? degsum : osum;
        const int ntb  = (msum + 15) >> 4;

        if (hf == 0 && lane < 32) {
            const int which = lane >> 4;
            const int rr = r0 + which;
            if (rr < N)
                *(bf16x8*)(&bsl[ps][which][(lane & 15) * 8]) =
                    *(const bf16x8*)(AB + (size_t)rr * 256 + 128 + (lane & 15) * 8);
        }

        float ca0[4] = {0, 0, 0, 0};
        float ca1[4] = {0, 0, 0, 0};

        float d_c = 0.0f; int rs_c = 0;
        bf16x8 a_c0 = {}, a_c1 = {};
        if (ntb > 0) {
            const int cl = (degsum > 0) ? ((row < degsum) ? row : degsum - 1) : 0;
            const int gi = (degsum > 0) ? w0 + cl : 0;
            const int s0 = csr_s[gi];
            d_c  = dist[gi];
            rs_c = (degsum > 0 && cl >= deg0) ? 1 : 0;
            const int kb0 = hf * 8 + kq * 2;
            a_c0 = *(const bf16x8*)(AB + (size_t)s0 * 256 + kb0 * 8);
            a_c1 = *(const bf16x8*)(AB + (size_t)s0 * 256 + (kb0 + 1) * 8);
        }
        __syncthreads();                       // bsl ready; prev Q done

        for (int tile = 0; tile < ntb; ++tile) {
            __bf16* hbuf = &hd[ps][tile & 1][0];

            int s_n = 0; float d_n = 0.0f; int rs_n = 0;
            const bool more = (tile + 1 < ntb);
            if (more) {
                const int el2 = (tile + 1) * 16 + row;
                const int cl2 = (degsum > 0) ? ((el2 < degsum) ? el2 : degsum - 1) : 0;
                const int gi2 = (degsum > 0) ? w0 + cl2 : 0;
                s_n  = csr_s[gi2];
                d_n  = dist[gi2];
                rs_n = (degsum > 0 && cl2 >= deg0) ? 1 : 0;
            }

            // ---- phase 1: my k-half of the first layer (prefetched A) -----
            {
                const int kb0 = hf * 8 + kq * 2;
#pragma unroll
                for (int i = 0; i < 2; ++i) {
                    const int kb = kb0 + i;
                    const int k0 = kb * 8;
                    bf16x8 a  = (i == 0) ? a_c0 : a_c1;
                    bf16x8 bb = *(const bf16x8*)(&bsl[ps][rs_c][k0]);
                    float4 w0f = *(const float4*)(w3s + k0);
                    float4 w1f = *(const float4*)(w3s + k0 + 4);
                    bf16x8 af;
                    af[0] = (__bf16)silu_f((float)a[0] + (float)bb[0] + d_c * w0f.x);
                    af[1] = (__bf16)silu_f((float)a[1] + (float)bb[1] + d_c * w0f.y);
                    af[2] = (__bf16)silu_f((float)a[2] + (float)bb[2] + d_c * w0f.z);
                    af[3] = (__bf16)silu_f((float)a[3] + (float)bb[3] + d_c * w0f.w);
                    af[4] = (__bf16)silu_f((float)a[4] + (float)bb[4] + d_c * w1f.x);
                    af[5] = (__bf16)silu_f((float)a[5] + (float)bb[5] + d_c * w1f.y);
                    af[6] = (__bf16)silu_f((float)a[6] + (float)bb[6] + d_c * w1f.z);
                    af[7] = (__bf16)silu_f((float)a[7] + (float)bb[7] + d_c * w1f.w);
                    *(bf16x8*)(hbuf + row * 136 + kb * 8) = af;
                }
            }

            if (more) {
                const int kb0 = hf * 8 + kq * 2;
                a_c0 = *(const bf16x8*)(AB + (size_t)s_n * 256 + kb0 * 8);
                a_c1 = *(const bf16x8*)(AB + (size_t)s_n * 256 + (kb0 + 1) * 8);
            }
            __syncthreads();                   // h-tile complete

            // ---- phase 2: my column half over the full-k h-tile -----------
            f32x4 acc[4] = {};
#pragma unroll
            for (int c = 0; c < 4; ++c) {
                const int kb2 = c * 4 + kq;
                bf16x8 af = *(const bf16x8*)(hbuf + row * 136 + kb2 * 8);
#pragma unroll
                for (int t4 = 0; t4 < 4; ++t4) {
                    const int j  = (hf * 4 + t4) * 16 + row;
                    const int jb = j & 7;
                    bf16x8 b = *(const bf16x8*)(wt + (j << 7) + ((kb2 ^ jb) << 3));
                    acc[t4] = MFMA16(af, b, acc[t4], 0, 0, 0);
                }
            }
#pragma unroll
            for (int t4 = 0; t4 < 4; ++t4) {
                const float bb = b2s[(hf * 4 + t4) * 16 + row];
#pragma unroll
                for (int q = 0; q < 4; ++q) {
                    const int er = tile * 16 + kq * 4 + q;   // combined window
                    if (er < degsum) {
                        float v = silu_f(acc[t4][q] + bb);
                        if (er < deg0) ca0[t4] += v; else ca1[t4] += v;
                    }
                }
            }

            d_c = d_n; rs_c = rs_n;
        }

#pragma unroll
        for (int t4 = 0; t4 < 4; ++t4) {
            float u0 = ca0[t4], u1 = ca1[t4];
            u0 += __shfl_xor(u0, 16, 64); u0 += __shfl_xor(u0, 32, 64);
            u1 += __shfl_xor(u1, 16, 64); u1 += __shfl_xor(u1, 32, 64);
            ca0[t4] = u0; ca1[t4] = u1;
        }
        if (kq == 0) {
#pragma unroll
            for (int t4 = 0; t4 < 4; ++t4) {
                if (v0) aggr[(size_t)r0 * 128 + (hf * 4 + t4) * 16 + row] = ca0[t4];
                if (v1) aggr[(size_t)r1 * 128 + (hf * 4 + t4) * 16 + row] = ca1[t4];
            }
        }
    }
}

// -------- phase 3: u = silu(x@U1a + aggr@U1b + c1), bf16, IN PLACE over aggr
__global__ __launch_bounds__(256) void k_node2(
    const float* __restrict__ x, const float* __restrict__ aggr,
    const float* __restrict__ U1, const float* __restrict__ c1,
    __bf16* __restrict__ u, int N, int ngroups)
{
    __shared__ __bf16 wt[128 * 256];
    for (int idx = threadIdx.x; idx < 128 * 256; idx += 256) {
        int j = idx & 127, k = idx >> 7;
        wt[(j << 8) + ((((k >> 3) ^ (j & 7))) << 3) + (k & 7)] = (__bf16)U1[(k << 7) + j];
    }
    __syncthreads();

    const int lane = threadIdx.x & 63;
    const int row  = lane & 15;
    const int kq   = lane >> 4;

    for (int g = blockIdx.x; g < ngroups; g += gridDim.x) {
        const int row0 = g * 64 + (threadIdx.x >> 6) * 16;
        int m = row0 + row; if (m >= N) m = N - 1;

        bf16x8 afr[8];
#pragma unroll
        for (int c = 0; c < 8; ++c) {
            const int k0 = (c & 3) * 32 + kq * 8;
            const float* src = (c < 4) ? (x + (size_t)m * 128 + k0)
                                       : (aggr + (size_t)m * 128 + k0);
            float4 a0 = *(const float4*)(src);
            float4 a1 = *(const float4*)(src + 4);
            bf16x8 af;
            af[0]=(__bf16)a0.x; af[1]=(__bf16)a0.y; af[2]=(__bf16)a0.z; af[3]=(__bf16)a0.w;
            af[4]=(__bf16)a1.x; af[5]=(__bf16)a1.y; af[6]=(__bf16)a1.z; af[7]=(__bf16)a1.w;
            afr[c] = af;
        }

        f32x4 acc[8] = {};
#pragma unroll
        for (int t = 0; t < 8; ++t) {
            const int j  = t * 16 + row;
            const int jb = j & 7;
            const __bf16* base = wt + (j << 8);
#pragma unroll
            for (int c = 0; c < 8; ++c) {
                const int kb = c * 4 + kq;
                bf16x8 b = *(const bf16x8*)(base + ((kb ^ jb) << 3));
                acc[t] = MFMA16(afr[c], b, acc[t], 0, 0, 0);
            }
        }

#pragma unroll
        for (int t = 0; t < 8; ++t) {
            const int col = t * 16 + row;
            const float cc = c1[col];
#pragma unroll
            for (int q = 0; q < 4; ++q) {
                const int gr = row0 + kq * 4 + q;
                if (gr < N) u[(size_t)gr * 256 + col] = (__bf16)silu_f(acc[t][q] + cc);
            }
        }
    }
}

// ---------------- phase 4: out = u@U2 + c2 (overwrites AB in d_out) ---------
__global__ __launch_bounds__(256) void k_node3(
    const __bf16* __restrict__ u, const float* __restrict__ U2,
    const float* __restrict__ c2, float* __restrict__ out, int N, int ngroups)
{
    __shared__ __bf16 wt[128 * 128];
    for (int idx = threadIdx.x; idx < 128 * 128; idx += 256) {
        int j = idx & 127, k = idx >> 7;
        wt[(j << 7) + ((((k >> 3) ^ (j & 7))) << 3) + (k & 7)] = (__bf16)U2[(k << 7) + j];
    }
    __syncthreads();

    const int lane = threadIdx.x & 63;
    const int row  = lane & 15;
    const int kq   = lane >> 4;

    for (int g = blockIdx.x; g < ngroups; g += gridDim.x) {
        const int row0 = g * 64 + (threadIdx.x >> 6) * 16;
        int m = row0 + row; if (m >= N) m = N - 1;

        bf16x8 afr[4];
#pragma unroll
        for (int c = 0; c < 4; ++c) {
            const int k0 = c * 32 + kq * 8;
            afr[c] = *(const bf16x8*)(u + (size_t)m * 256 + k0);
        }

        f32x4 acc[8] = {};
#pragma unroll
        for (int t = 0; t < 8; ++t) {
            const int j  = t * 16 + row;
            const int jb = j & 7;
            const __bf16* base = wt + (j << 7);
#pragma unroll
            for (int c = 0; c < 4; ++c) {
                const int kb = c * 4 + kq;
                bf16x8 b = *(const bf16x8*)(base + ((kb ^ jb) << 3));
                acc[t] = MFMA16(afr[c], b, acc[t], 0, 0, 0);
            }
        }

#pragma unroll
        for (int t = 0; t < 8; ++t) {
            const int col = t * 16 + row;
            const float cc = c2[col];
#pragma unroll
            for (int q = 0; q < 4; ++q) {
                const int gr = row0 + kq * 4 + q;
                if (gr < N) out[(size_t)gr * 128 + col] = acc[t][q] + cc;
            }
        }
    }
}

extern "C" void kernel_launch(void* const* d_in, const int* in_sizes, int n_in,
                              void* d_out, int out_size, void* d_ws, size_t ws_size,
                              hipStream_t stream) {
    (void)n_in; (void)out_size;
    const float* x   = (const float*)d_in[0];
    const float* pos = (const float*)d_in[1];
    const int*   ei  = (const int*)d_in[2];
    const float* W1  = (const float*)d_in[3];
    const float* b1  = (const float*)d_in[4];
    const float* W2  = (const float*)d_in[5];
    const float* b2  = (const float*)d_in[6];
    const float* U1  = (const float*)d_in[7];
    const float* c1  = (const float*)d_in[8];
    const float* U2  = (const float*)d_in[9];
    const float* c2  = (const float*)d_in[10];

    const int N = in_sizes[0] / 128;
    const int E = in_sizes[2] / 2;

    // ---- workspace layout (16B-aligned slabs) ----
    const size_t aggr_b = (size_t)N * 128 * sizeof(float);
    const size_t Ni_b   = (((size_t)N * 4) + 15) & ~(size_t)15;
    const size_t E_b    = (((size_t)E * 4) + 15) & ~(size_t)15;
    size_t off = 0;
    char* base = (char*)d_ws;
    float* aggr   = (float*)(base + off); off += aggr_b;
    int*   flag   = (int*)  (base + off); off += 16;
    int*   counts = (int*)  (base + off); off += Ni_b;
    int*   offs   = (int*)  (base + off); off += Ni_b;
    int*   cursor = (int*)  (base + off); off += Ni_b;
    int*   csr_s  = (int*)  (base + off); off += E_b;
    int*   csr_r  = (int*)  (base + off); off += E_b;
    float* dist   = (float*)(base + off); off += E_b;
    const size_t need_csr = off;

    __bf16* u  = (__bf16*)d_ws;        // row stride 256 elem, aliases aggr
    __bf16* AB = (__bf16*)d_out;       // N*256 bf16 == out_nbytes

    const bool csr_ok = (ws_size >= need_csr);
    if (ws_size < aggr_b + 16 || !csr_ok) return;

    const int ng_nodes = (N + 63) / 64;
    const int grid_n   = ng_nodes < 512 ? ng_nodes : 512;
    const int grid_E   = (E + 255) / 256;
    const int nquad    = (N + 3) / 4;
    const int grid_q   = nquad < 2048 ? nquad : 2048;

    k_detect<<<1, 256, 0, stream>>>(ei, flag);
    k_node1<<<grid_n, 256, 0, stream>>>(x, W1, b1, AB, N, ng_nodes);

    hipMemsetAsync(counts, 0, (size_t)N * 4, stream);
    k_hist   <<<grid_E, 256, 0, stream>>>(ei, flag, counts, E);
    k_scanall<<<1, 1024, 0, stream>>>(counts, offs, cursor, N);
    k_scatter<<<grid_E, 256, 0, stream>>>(ei, flag, pos, cursor,
                                          csr_s, csr_r, dist, E);

    k_edge_p3<<<grid_q, 256, 0, stream>>>(AB, csr_s, dist, offs, counts,
                                          W2, b2, W1 + 256 * 128, aggr, N);

    k_node2<<<grid_n, 256, 0, stream>>>(x, aggr, U1, c1, u, N, ng_nodes);
    k_node3<<<grid_n, 256, 0, stream>>>(u, U2, c2, (float*)d_out, N, ng_nodes);
}

// Round 24
// 337.416 us; speedup vs baseline: 1.3049x; 1.3049x over previous
//
#include <hip/hip_runtime.h>
#include <hip/hip_bf16.h>
#include <math.h>

typedef __bf16 bf16x8 __attribute__((ext_vector_type(8)));
typedef float  f32x4  __attribute__((ext_vector_type(4)));

#define MFMA16 __builtin_amdgcn_mfma_f32_16x16x32_bf16

__device__ __forceinline__ float silu_f(float v) {
    return v * __builtin_amdgcn_rcpf(1.0f + __expf(-v));
}

// LDS weight layout: Wt[j][k], bf16, 16B-chunk XOR swizzle:
// phys = j*K + (((k>>3) ^ (j&7))<<3) + (k&7)  -> ds_read_b128, 2-way max.

// ---- detector: is edge_index stored as int64 (odd words all zero)? ---------
__global__ void k_detect(const int* __restrict__ ei, int* __restrict__ flag) {
    __shared__ int red[256];
    int v = 0;
#pragma unroll
    for (int j = 0; j < 4; ++j) v |= ei[2 * (threadIdx.x * 4 + j) + 1];
    red[threadIdx.x] = v;
    __syncthreads();
    for (int s = 128; s > 0; s >>= 1) {
        if (threadIdx.x < s) red[threadIdx.x] |= red[threadIdx.x + s];
        __syncthreads();
    }
    if (threadIdx.x == 0) *flag = (red[0] == 0) ? 1 : 0;
}

// ---- CSR build --------------------------------------------------------------
__global__ __launch_bounds__(256) void k_hist(
    const int* __restrict__ ei, const int* __restrict__ flag,
    int* __restrict__ counts, int E)
{
    int e = blockIdx.x * 256 + threadIdx.x;
    if (e >= E) return;
    const int is64 = *flag;
    int r = is64 ? ei[2 * E + 2 * e] : ei[E + e];
    atomicAdd(&counts[r], 1);
}

__global__ __launch_bounds__(256) void k_scan1(
    const int* __restrict__ counts, int* __restrict__ offsets,
    int* __restrict__ partials, int N)
{
    __shared__ int pairv[256];
    __shared__ int buf[256];
    const int t = threadIdx.x;
    const int base = blockIdx.x * 512;
    int a = (base + 2 * t     < N) ? counts[base + 2 * t]     : 0;
    int b = (base + 2 * t + 1 < N) ? counts[base + 2 * t + 1] : 0;
    pairv[t] = a + b;
    buf[t]   = a + b;
    __syncthreads();
    for (int d = 1; d < 256; d <<= 1) {
        int v = buf[t];
        int w = (t >= d) ? buf[t - d] : 0;
        __syncthreads();
        buf[t] = v + w;
        __syncthreads();
    }
    int excl = buf[t] - pairv[t];
    if (base + 2 * t     < N) offsets[base + 2 * t]     = excl;
    if (base + 2 * t + 1 < N) offsets[base + 2 * t + 1] = excl + a;
    if (t == 255) partials[blockIdx.x] = buf[255];
}

__global__ void k_scan2(int* __restrict__ partials, int nblk) {
    __shared__ int buf[256];
    const int t = threadIdx.x;
    int v0 = (t < nblk) ? partials[t] : 0;
    buf[t] = v0;
    __syncthreads();
    for (int d = 1; d < 256; d <<= 1) {
        int v = buf[t];
        int w = (t >= d) ? buf[t - d] : 0;
        __syncthreads();
        buf[t] = v + w;
        __syncthreads();
    }
    if (t < nblk) partials[t] = buf[t] - v0;   // exclusive
}

__global__ __launch_bounds__(256) void k_scan3(
    int* __restrict__ offsets, const int* __restrict__ partials,
    int* __restrict__ cursor, int N)
{
    int i = blockIdx.x * 256 + threadIdx.x;
    if (i >= N) return;
    int v = offsets[i] + partials[i >> 9];
    offsets[i] = v;
    cursor[i]  = v;
}

// scatter + per-edge distance precompute (kills pos-gather chains downstream)
__global__ __launch_bounds__(256) void k_scatter(
    const int* __restrict__ ei, const int* __restrict__ flag,
    const float* __restrict__ pos, int* __restrict__ cursor,
    int* __restrict__ csr_s, int* __restrict__ csr_r,
    float* __restrict__ dist, int E)
{
    int e = blockIdx.x * 256 + threadIdx.x;
    if (e >= E) return;
    const int is64 = *flag;
    int s, r;
    if (is64) { s = ei[2 * e]; r = ei[2 * E + 2 * e]; }
    else      { s = ei[e];     r = ei[E + e];         }
    float dx = pos[3 * s]     - pos[3 * r];
    float dy = pos[3 * s + 1] - pos[3 * r + 1];
    float dz = pos[3 * s + 2] - pos[3 * r + 2];
    float d  = sqrtf(dx * dx + dy * dy + dz * dz);
    int slot = atomicAdd(&cursor[r], 1);
    csr_s[slot] = s;
    csr_r[slot] = r;
    dist[slot]  = d;
}

// ---- phase 1: AB[n][0:128]=bf16(x@W1a + b1), AB[n][128:256]=bf16(x@W1b) ----
__global__ __launch_bounds__(256) void k_node1(
    const float* __restrict__ x, const float* __restrict__ W1,
    const float* __restrict__ b1, __bf16* __restrict__ AB, int N, int ngroups)
{
    __shared__ __bf16 wt[256 * 128];
    for (int idx = threadIdx.x; idx < 256 * 128; idx += 256) {
        int j = idx & 255, k = idx >> 8;
        float w = (j < 128) ? W1[(k << 7) + j] : W1[((k + 128) << 7) + (j - 128)];
        wt[(j << 7) + ((((k >> 3) ^ (j & 7))) << 3) + (k & 7)] = (__bf16)w;
    }
    __syncthreads();

    const int lane = threadIdx.x & 63;
    const int row  = lane & 15;
    const int kq   = lane >> 4;

    for (int g = blockIdx.x; g < ngroups; g += gridDim.x) {
        const int row0 = g * 64 + (threadIdx.x >> 6) * 16;
        int m = row0 + row; if (m >= N) m = N - 1;
        const float* xr = x + (size_t)m * 128;

        bf16x8 afr[4];
#pragma unroll
        for (int c = 0; c < 4; ++c) {
            const int k0 = c * 32 + kq * 8;
            float4 a0 = *(const float4*)(xr + k0);
            float4 a1 = *(const float4*)(xr + k0 + 4);
            bf16x8 af;
            af[0]=(__bf16)a0.x; af[1]=(__bf16)a0.y; af[2]=(__bf16)a0.z; af[3]=(__bf16)a0.w;
            af[4]=(__bf16)a1.x; af[5]=(__bf16)a1.y; af[6]=(__bf16)a1.z; af[7]=(__bf16)a1.w;
            afr[c] = af;
        }

        f32x4 acc[16] = {};
#pragma unroll
        for (int t = 0; t < 16; ++t) {
            const int j  = t * 16 + row;
            const int jb = j & 7;
            const __bf16* base = wt + (j << 7);
#pragma unroll
            for (int c = 0; c < 4; ++c) {
                const int kb = c * 4 + kq;
                bf16x8 b = *(const bf16x8*)(base + ((kb ^ jb) << 3));
                acc[t] = MFMA16(afr[c], b, acc[t], 0, 0, 0);
            }
        }

#pragma unroll
        for (int t = 0; t < 16; ++t) {
            const int col = t * 16 + row;
            const float bb = (col < 128) ? b1[col] : 0.0f;
#pragma unroll
            for (int q = 0; q < 4; ++q) {
                const int gr = row0 + kq * 4 + q;
                if (gr < N) AB[(size_t)gr * 256 + col] = (__bf16)(acc[t][q] + bb);
            }
        }
    }
}

// ---- FUSED edge v11 (k_edge_p3): wave-pair per RECEIVER-PAIR window --------
// Proven config (r21/r23: 68 VGPR, 166-168 us). Combined contiguous pair
// window, k-half split first layer via double-buffered padded LDS h-tile,
// software prefetch of next tile's indices and A-chunks.
__global__ __launch_bounds__(256) void k_edge_p3(
    const __bf16* __restrict__ AB, const int* __restrict__ csr_s,
    const float* __restrict__ dist, const int* __restrict__ offs,
    const int* __restrict__ counts, const float* __restrict__ W2,
    const float* __restrict__ b2, const float* __restrict__ w3,
    float* __restrict__ aggr, int N)
{
    __shared__ __bf16 wt[128 * 128];          // 32 KB W2^T swizzled
    __shared__ float  w3s[128];
    __shared__ float  b2s[128];
    __shared__ __bf16 bsl[2][2][128];         // [pair-slot][rcv-of-pair] B-row
    __shared__ __bf16 hd[2][2][16 * 136];     // [pair-slot][buf] padded h-tile
    for (int idx = threadIdx.x; idx < 128 * 128; idx += 256) {
        int j = idx & 127, k = idx >> 7;
        wt[(j << 7) + ((((k >> 3) ^ (j & 7))) << 3) + (k & 7)] = (__bf16)W2[(k << 7) + j];
    }
    for (int i = threadIdx.x; i < 128; i += 256) { w3s[i] = w3[i]; b2s[i] = b2[i]; }
    __syncthreads();

    const int lane = threadIdx.x & 63;
    const int row  = lane & 15;
    const int kq   = lane >> 4;
    const int wid  = threadIdx.x >> 6;
    const int ps   = wid >> 1;
    const int hf   = wid & 1;
    const int nquad = (N + 3) >> 2;

    for (int Q = blockIdx.x; Q < nquad; Q += gridDim.x) {
        const int r0 = 4 * Q + 2 * ps;
        const int r1 = r0 + 1;
        const bool v0 = (r0 < N), v1 = (r1 < N);
        const int w0   = v0 ? offs[r0]   : 0;
        const int deg0 = v0 ? counts[r0] : 0;
        const int deg1 = v1 ? counts[r1] : 0;
        const int degsum = deg0 + deg1;
        const int o0  = 4 * Q + 2 * (ps ^ 1);
        const int od0 = (o0 < N)     ? counts[o0]     : 0;
        const int od1 = (o0 + 1 < N) ? counts[o0 + 1] : 0;
        const int osum = od0 + od1;
        const int msum = degsum > osum ? degsum : osum;
        const int ntb  = (msum + 15) >> 4;

        if (hf == 0 && lane < 32) {
            const int which = lane >> 4;
            const int rr = r0 + which;
            if (rr < N)
                *(bf16x8*)(&bsl[ps][which][(lane & 15) * 8]) =
                    *(const bf16x8*)(AB + (size_t)rr * 256 + 128 + (lane & 15) * 8);
        }

        float ca0[4] = {0, 0, 0, 0};
        float ca1[4] = {0, 0, 0, 0};

        float d_c = 0.0f; int rs_c = 0;
        bf16x8 a_c0 = {}, a_c1 = {};
        if (ntb > 0) {
            const int cl = (degsum > 0) ? ((row < degsum) ? row : degsum - 1) : 0;
            const int gi = (degsum > 0) ? w0 + cl : 0;
            const int s0 = csr_s[gi];
            d_c  = dist[gi];
            rs_c = (degsum > 0 && cl >= deg0) ? 1 : 0;
            const int kb0 = hf * 8 + kq * 2;
            a_c0 = *(const bf16x8*)(AB + (size_t)s0 * 256 + kb0 * 8);
            a_c1 = *(const bf16x8*)(AB + (size_t)s0 * 256 + (kb0 + 1) * 8);
        }
        __syncthreads();                       // bsl ready; prev Q done

        for (int tile = 0; tile < ntb; ++tile) {
            __bf16* hbuf = &hd[ps][tile & 1][0];

            int s_n = 0; float d_n = 0.0f; int rs_n = 0;
            const bool more = (tile + 1 < ntb);
            if (more) {
                const int el2 = (tile + 1) * 16 + row;
                const int cl2 = (degsum > 0) ? ((el2 < degsum) ? el2 : degsum - 1) : 0;
                const int gi2 = (degsum > 0) ? w0 + cl2 : 0;
                s_n  = csr_s[gi2];
                d_n  = dist[gi2];
                rs_n = (degsum > 0 && cl2 >= deg0) ? 1 : 0;
            }

            // ---- phase 1: my k-half of the first layer (prefetched A) -----
            {
                const int kb0 = hf * 8 + kq * 2;
#pragma unroll
                for (int i = 0; i < 2; ++i) {
                    const int kb = kb0 + i;
                    const int k0 = kb * 8;
                    bf16x8 a  = (i == 0) ? a_c0 : a_c1;
                    bf16x8 bb = *(const bf16x8*)(&bsl[ps][rs_c][k0]);
                    float4 w0f = *(const float4*)(w3s + k0);
                    float4 w1f = *(const float4*)(w3s + k0 + 4);
                    bf16x8 af;
                    af[0] = (__bf16)silu_f((float)a[0] + (float)bb[0] + d_c * w0f.x);
                    af[1] = (__bf16)silu_f((float)a[1] + (float)bb[1] + d_c * w0f.y);
                    af[2] = (__bf16)silu_f((float)a[2] + (float)bb[2] + d_c * w0f.z);
                    af[3] = (__bf16)silu_f((float)a[3] + (float)bb[3] + d_c * w0f.w);
                    af[4] = (__bf16)silu_f((float)a[4] + (float)bb[4] + d_c * w1f.x);
                    af[5] = (__bf16)silu_f((float)a[5] + (float)bb[5] + d_c * w1f.y);
                    af[6] = (__bf16)silu_f((float)a[6] + (float)bb[6] + d_c * w1f.z);
                    af[7] = (__bf16)silu_f((float)a[7] + (float)bb[7] + d_c * w1f.w);
                    *(bf16x8*)(hbuf + row * 136 + kb * 8) = af;
                }
            }

            if (more) {
                const int kb0 = hf * 8 + kq * 2;
                a_c0 = *(const bf16x8*)(AB + (size_t)s_n * 256 + kb0 * 8);
                a_c1 = *(const bf16x8*)(AB + (size_t)s_n * 256 + (kb0 + 1) * 8);
            }
            __syncthreads();                   // h-tile complete

            // ---- phase 2: my column half over the full-k h-tile -----------
            f32x4 acc[4] = {};
#pragma unroll
            for (int c = 0; c < 4; ++c) {
                const int kb2 = c * 4 + kq;
                bf16x8 af = *(const bf16x8*)(hbuf + row * 136 + kb2 * 8);
#pragma unroll
                for (int t4 = 0; t4 < 4; ++t4) {
                    const int j  = (hf * 4 + t4) * 16 + row;
                    const int jb = j & 7;
                    bf16x8 b = *(const bf16x8*)(wt + (j << 7) + ((kb2 ^ jb) << 3));
                    acc[t4] = MFMA16(af, b, acc[t4], 0, 0, 0);
                }
            }
#pragma unroll
            for (int t4 = 0; t4 < 4; ++t4) {
                const float bb = b2s[(hf * 4 + t4) * 16 + row];
#pragma unroll
                for (int q = 0; q < 4; ++q) {
                    const int er = tile * 16 + kq * 4 + q;   // combined window
                    if (er < degsum) {
                        float v = silu_f(acc[t4][q] + bb);
                        if (er < deg0) ca0[t4] += v; else ca1[t4] += v;
                    }
                }
            }

            d_c = d_n; rs_c = rs_n;
        }

#pragma unroll
        for (int t4 = 0; t4 < 4; ++t4) {
            float u0 = ca0[t4], u1 = ca1[t4];
            u0 += __shfl_xor(u0, 16, 64); u0 += __shfl_xor(u0, 32, 64);
            u1 += __shfl_xor(u1, 16, 64); u1 += __shfl_xor(u1, 32, 64);
            ca0[t4] = u0; ca1[t4] = u1;
        }
        if (kq == 0) {
#pragma unroll
            for (int t4 = 0; t4 < 4; ++t4) {
                if (v0) aggr[(size_t)r0 * 128 + (hf * 4 + t4) * 16 + row] = ca0[t4];
                if (v1) aggr[(size_t)r1 * 128 + (hf * 4 + t4) * 16 + row] = ca1[t4];
            }
        }
    }
}

// -------- phase 3: u = silu(x@U1a + aggr@U1b + c1), bf16, IN PLACE over aggr
__global__ __launch_bounds__(256) void k_node2(
    const float* __restrict__ x, const float* __restrict__ aggr,
    const float* __restrict__ U1, const float* __restrict__ c1,
    __bf16* __restrict__ u, int N, int ngroups)
{
    __shared__ __bf16 wt[128 * 256];
    for (int idx = threadIdx.x; idx < 128 * 256; idx += 256) {
        int j = idx & 127, k = idx >> 7;
        wt[(j << 8) + ((((k >> 3) ^ (j & 7))) << 3) + (k & 7)] = (__bf16)U1[(k << 7) + j];
    }
    __syncthreads();

    const int lane = threadIdx.x & 63;
    const int row  = lane & 15;
    const int kq   = lane >> 4;

    for (int g = blockIdx.x; g < ngroups; g += gridDim.x) {
        const int row0 = g * 64 + (threadIdx.x >> 6) * 16;
        int m = row0 + row; if (m >= N) m = N - 1;

        bf16x8 afr[8];
#pragma unroll
        for (int c = 0; c < 8; ++c) {
            const int k0 = (c & 3) * 32 + kq * 8;
            const float* src = (c < 4) ? (x + (size_t)m * 128 + k0)
                                       : (aggr + (size_t)m * 128 + k0);
            float4 a0 = *(const float4*)(src);
            float4 a1 = *(const float4*)(src + 4);
            bf16x8 af;
            af[0]=(__bf16)a0.x; af[1]=(__bf16)a0.y; af[2]=(__bf16)a0.z; af[3]=(__bf16)a0.w;
            af[4]=(__bf16)a1.x; af[5]=(__bf16)a1.y; af[6]=(__bf16)a1.z; af[7]=(__bf16)a1.w;
            afr[c] = af;
        }

        f32x4 acc[8] = {};
#pragma unroll
        for (int t = 0; t < 8; ++t) {
            const int j  = t * 16 + row;
            const int jb = j & 7;
            const __bf16* base = wt + (j << 8);
#pragma unroll
            for (int c = 0; c < 8; ++c) {
                const int kb = c * 4 + kq;
                bf16x8 b = *(const bf16x8*)(base + ((kb ^ jb) << 3));
                acc[t] = MFMA16(afr[c], b, acc[t], 0, 0, 0);
            }
        }

#pragma unroll
        for (int t = 0; t < 8; ++t) {
            const int col = t * 16 + row;
            const float cc = c1[col];
#pragma unroll
            for (int q = 0; q < 4; ++q) {
                const int gr = row0 + kq * 4 + q;
                if (gr < N) u[(size_t)gr * 256 + col] = (__bf16)silu_f(acc[t][q] + cc);
            }
        }
    }
}

// ---------------- phase 4: out = u@U2 + c2 (overwrites AB in d_out) ---------
__global__ __launch_bounds__(256) void k_node3(
    const __bf16* __restrict__ u, const float* __restrict__ U2,
    const float* __restrict__ c2, float* __restrict__ out, int N, int ngroups)
{
    __shared__ __bf16 wt[128 * 128];
    for (int idx = threadIdx.x; idx < 128 * 128; idx += 256) {
        int j = idx & 127, k = idx >> 7;
        wt[(j << 7) + ((((k >> 3) ^ (j & 7))) << 3) + (k & 7)] = (__bf16)U2[(k << 7) + j];
    }
    __syncthreads();

    const int lane = threadIdx.x & 63;
    const int row  = lane & 15;
    const int kq   = lane >> 4;

    for (int g = blockIdx.x; g < ngroups; g += gridDim.x) {
        const int row0 = g * 64 + (threadIdx.x >> 6) * 16;
        int m = row0 + row; if (m >= N) m = N - 1;

        bf16x8 afr[4];
#pragma unroll
        for (int c = 0; c < 4; ++c) {
            const int k0 = c * 32 + kq * 8;
            afr[c] = *(const bf16x8*)(u + (size_t)m * 256 + k0);
        }

        f32x4 acc[8] = {};
#pragma unroll
        for (int t = 0; t < 8; ++t) {
            const int j  = t * 16 + row;
            const int jb = j & 7;
            const __bf16* base = wt + (j << 7);
#pragma unroll
            for (int c = 0; c < 4; ++c) {
                const int kb = c * 4 + kq;
                bf16x8 b = *(const bf16x8*)(base + ((kb ^ jb) << 3));
                acc[t] = MFMA16(afr[c], b, acc[t], 0, 0, 0);
            }
        }

#pragma unroll
        for (int t = 0; t < 8; ++t) {
            const int col = t * 16 + row;
            const float cc = c2[col];
#pragma unroll
            for (int q = 0; q < 4; ++q) {
                const int gr = row0 + kq * 4 + q;
                if (gr < N) out[(size_t)gr * 128 + col] = acc[t][q] + cc;
            }
        }
    }
}

extern "C" void kernel_launch(void* const* d_in, const int* in_sizes, int n_in,
                              void* d_out, int out_size, void* d_ws, size_t ws_size,
                              hipStream_t stream) {
    (void)n_in; (void)out_size;
    const float* x   = (const float*)d_in[0];
    const float* pos = (const float*)d_in[1];
    const int*   ei  = (const int*)d_in[2];
    const float* W1  = (const float*)d_in[3];
    const float* b1  = (const float*)d_in[4];
    const float* W2  = (const float*)d_in[5];
    const float* b2  = (const float*)d_in[6];
    const float* U1  = (const float*)d_in[7];
    const float* c1  = (const float*)d_in[8];
    const float* U2  = (const float*)d_in[9];
    const float* c2  = (const float*)d_in[10];

    const int N = in_sizes[0] / 128;
    const int E = in_sizes[2] / 2;

    // ---- workspace layout (16B-aligned slabs) ----
    const size_t aggr_b = (size_t)N * 128 * sizeof(float);
    const size_t Ni_b   = (((size_t)N * 4) + 15) & ~(size_t)15;
    const size_t E_b    = (((size_t)E * 4) + 15) & ~(size_t)15;
    size_t off = 0;
    char* base = (char*)d_ws;
    float* aggr   = (float*)(base + off); off += aggr_b;
    int*   flag   = (int*)  (base + off); off += 16;
    int*   counts = (int*)  (base + off); off += Ni_b;
    int*   offs   = (int*)  (base + off); off += Ni_b;
    int*   cursor = (int*)  (base + off); off += Ni_b;
    int*   parts  = (int*)  (base + off); off += 256 * 4;
    int*   csr_s  = (int*)  (base + off); off += E_b;
    int*   csr_r  = (int*)  (base + off); off += E_b;
    float* dist   = (float*)(base + off); off += E_b;
    const size_t need_csr = off;

    __bf16* u  = (__bf16*)d_ws;        // row stride 256 elem, aliases aggr
    __bf16* AB = (__bf16*)d_out;       // N*256 bf16 == out_nbytes

    const int nblk_scan = (N + 511) / 512;
    const bool csr_ok = (ws_size >= need_csr) && (nblk_scan <= 256);
    if (ws_size < aggr_b + 16 || !csr_ok) return;

    const int ng_nodes = (N + 63) / 64;
    const int grid_n1  = ng_nodes < 2048 ? ng_nodes : 2048;  // node1: exact grid
    const int grid_n   = ng_nodes < 512 ? ng_nodes : 512;
    const int grid_E   = (E + 255) / 256;
    const int grid_Nt  = (N + 255) / 256;
    const int nquad    = (N + 3) / 4;
    const int grid_q   = nquad < 2048 ? nquad : 2048;

    k_detect<<<1, 256, 0, stream>>>(ei, flag);
    k_node1<<<grid_n1, 256, 0, stream>>>(x, W1, b1, AB, N, ng_nodes);

    hipMemsetAsync(counts, 0, (size_t)N * 4, stream);
    k_hist   <<<grid_E, 256, 0, stream>>>(ei, flag, counts, E);
    k_scan1  <<<nblk_scan, 256, 0, stream>>>(counts, offs, parts, N);
    k_scan2  <<<1, 256, 0, stream>>>(parts, nblk_scan);
    k_scan3  <<<grid_Nt, 256, 0, stream>>>(offs, parts, cursor, N);
    k_scatter<<<grid_E, 256, 0, stream>>>(ei, flag, pos, cursor,
                                          csr_s, csr_r, dist, E);

    k_edge_p3<<<grid_q, 256, 0, stream>>>(AB, csr_s, dist, offs, counts,
                                          W2, b2, W1 + 256 * 128, aggr, N);

    k_node2<<<grid_n, 256, 0, stream>>>(x, aggr, U1, c1, u, N, ng_nodes);
    k_node3<<<grid_n, 256, 0, stream>>>(u, U2, c2, (float*)d_out, N, ng_nodes);
}

// Round 25
// 325.876 us; speedup vs baseline: 1.3511x; 1.0354x over previous
//
#include <hip/hip_runtime.h>
#include <hip/hip_bf16.h>
#include <math.h>

typedef __bf16 bf16x8 __attribute__((ext_vector_type(8)));
typedef float  f32x4  __attribute__((ext_vector_type(4)));

#define MFMA16 __builtin_amdgcn_mfma_f32_16x16x32_bf16

__device__ __forceinline__ float silu_f(float v) {
    return v * __builtin_amdgcn_rcpf(1.0f + __expf(-v));
}

// LDS weight layout: Wt[j][k], bf16, 16B-chunk XOR swizzle:
// phys = j*K + (((k>>3) ^ (j&7))<<3) + (k&7)  -> ds_read_b128, 2-way max.

// ---- detector: is edge_index stored as int64 (odd words all zero)? ---------
__global__ void k_detect(const int* __restrict__ ei, int* __restrict__ flag) {
    __shared__ int red[256];
    int v = 0;
#pragma unroll
    for (int j = 0; j < 4; ++j) v |= ei[2 * (threadIdx.x * 4 + j) + 1];
    red[threadIdx.x] = v;
    __syncthreads();
    for (int s = 128; s > 0; s >>= 1) {
        if (threadIdx.x < s) red[threadIdx.x] |= red[threadIdx.x + s];
        __syncthreads();
    }
    if (threadIdx.x == 0) *flag = (red[0] == 0) ? 1 : 0;
}

// ---- CSR build --------------------------------------------------------------
__global__ __launch_bounds__(256) void k_hist(
    const int* __restrict__ ei, const int* __restrict__ flag,
    int* __restrict__ counts, int E)
{
    int e = blockIdx.x * 256 + threadIdx.x;
    if (e >= E) return;
    const int is64 = *flag;
    int r = is64 ? ei[2 * E + 2 * e] : ei[E + e];
    atomicAdd(&counts[r], 1);
}

__global__ __launch_bounds__(256) void k_scan1(
    const int* __restrict__ counts, int* __restrict__ offsets,
    int* __restrict__ partials, int N)
{
    __shared__ int pairv[256];
    __shared__ int buf[256];
    const int t = threadIdx.x;
    const int base = blockIdx.x * 512;
    int a = (base + 2 * t     < N) ? counts[base + 2 * t]     : 0;
    int b = (base + 2 * t + 1 < N) ? counts[base + 2 * t + 1] : 0;
    pairv[t] = a + b;
    buf[t]   = a + b;
    __syncthreads();
    for (int d = 1; d < 256; d <<= 1) {
        int v = buf[t];
        int w = (t >= d) ? buf[t - d] : 0;
        __syncthreads();
        buf[t] = v + w;
        __syncthreads();
    }
    int excl = buf[t] - pairv[t];
    if (base + 2 * t     < N) offsets[base + 2 * t]     = excl;
    if (base + 2 * t + 1 < N) offsets[base + 2 * t + 1] = excl + a;
    if (t == 255) partials[blockIdx.x] = buf[255];
}

__global__ void k_scan2(int* __restrict__ partials, int nblk) {
    __shared__ int buf[256];
    const int t = threadIdx.x;
    int v0 = (t < nblk) ? partials[t] : 0;
    buf[t] = v0;
    __syncthreads();
    for (int d = 1; d < 256; d <<= 1) {
        int v = buf[t];
        int w = (t >= d) ? buf[t - d] : 0;
        __syncthreads();
        buf[t] = v + w;
        __syncthreads();
    }
    if (t < nblk) partials[t] = buf[t] - v0;   // exclusive
}

__global__ __launch_bounds__(256) void k_scan3(
    int* __restrict__ offsets, const int* __restrict__ partials,
    int* __restrict__ cursor, int N)
{
    int i = blockIdx.x * 256 + threadIdx.x;
    if (i >= N) return;
    int v = offsets[i] + partials[i >> 9];
    offsets[i] = v;
    cursor[i]  = v;
}

// scatter + per-edge distance precompute (kills pos-gather chains downstream)
__global__ __launch_bounds__(256) void k_scatter(
    const int* __restrict__ ei, const int* __restrict__ flag,
    const float* __restrict__ pos, int* __restrict__ cursor,
    int* __restrict__ csr_s, int* __restrict__ csr_r,
    float* __restrict__ dist, int E)
{
    int e = blockIdx.x * 256 + threadIdx.x;
    if (e >= E) return;
    const int is64 = *flag;
    int s, r;
    if (is64) { s = ei[2 * e]; r = ei[2 * E + 2 * e]; }
    else      { s = ei[e];     r = ei[E + e];         }
    float dx = pos[3 * s]     - pos[3 * r];
    float dy = pos[3 * s + 1] - pos[3 * r + 1];
    float dz = pos[3 * s + 2] - pos[3 * r + 2];
    float d  = sqrtf(dx * dx + dy * dy + dz * dz);
    int slot = atomicAdd(&cursor[r], 1);
    csr_s[slot] = s;
    csr_r[slot] = r;
    dist[slot]  = d;
}

// ---- phase 1: AB[n][0:128]=bf16(x@W1a + b1), AB[n][128:256]=bf16(x@W1b) ----
__global__ __launch_bounds__(256) void k_node1(
    const float* __restrict__ x, const float* __restrict__ W1,
    const float* __restrict__ b1, __bf16* __restrict__ AB, int N, int ngroups)
{
    __shared__ __bf16 wt[256 * 128];
    for (int idx = threadIdx.x; idx < 256 * 128; idx += 256) {
        int j = idx & 255, k = idx >> 8;
        float w = (j < 128) ? W1[(k << 7) + j] : W1[((k + 128) << 7) + (j - 128)];
        wt[(j << 7) + ((((k >> 3) ^ (j & 7))) << 3) + (k & 7)] = (__bf16)w;
    }
    __syncthreads();

    const int lane = threadIdx.x & 63;
    const int row  = lane & 15;
    const int kq   = lane >> 4;

    for (int g = blockIdx.x; g < ngroups; g += gridDim.x) {
        const int row0 = g * 64 + (threadIdx.x >> 6) * 16;
        int m = row0 + row; if (m >= N) m = N - 1;
        const float* xr = x + (size_t)m * 128;

        bf16x8 afr[4];
#pragma unroll
        for (int c = 0; c < 4; ++c) {
            const int k0 = c * 32 + kq * 8;
            float4 a0 = *(const float4*)(xr + k0);
            float4 a1 = *(const float4*)(xr + k0 + 4);
            bf16x8 af;
            af[0]=(__bf16)a0.x; af[1]=(__bf16)a0.y; af[2]=(__bf16)a0.z; af[3]=(__bf16)a0.w;
            af[4]=(__bf16)a1.x; af[5]=(__bf16)a1.y; af[6]=(__bf16)a1.z; af[7]=(__bf16)a1.w;
            afr[c] = af;
        }

        f32x4 acc[16] = {};
#pragma unroll
        for (int t = 0; t < 16; ++t) {
            const int j  = t * 16 + row;
            const int jb = j & 7;
            const __bf16* base = wt + (j << 7);
#pragma unroll
            for (int c = 0; c < 4; ++c) {
                const int kb = c * 4 + kq;
                bf16x8 b = *(const bf16x8*)(base + ((kb ^ jb) << 3));
                acc[t] = MFMA16(afr[c], b, acc[t], 0, 0, 0);
            }
        }

#pragma unroll
        for (int t = 0; t < 16; ++t) {
            const int col = t * 16 + row;
            const float bb = (col < 128) ? b1[col] : 0.0f;
#pragma unroll
            for (int q = 0; q < 4; ++q) {
                const int gr = row0 + kq * 4 + q;
                if (gr < N) AB[(size_t)gr * 256 + col] = (__bf16)(acc[t][q] + bb);
            }
        }
    }
}

// ---- FUSED edge v11 (k_edge_p3): wave-pair per RECEIVER-PAIR window --------
// Proven config (r21/r23/r24: 68 VGPR, 166-168 us). Combined contiguous pair
// window, k-half split first layer via double-buffered padded LDS h-tile,
// software prefetch of next tile's indices and A-chunks.
__global__ __launch_bounds__(256) void k_edge_p3(
    const __bf16* __restrict__ AB, const int* __restrict__ csr_s,
    const float* __restrict__ dist, const int* __restrict__ offs,
    const int* __restrict__ counts, const float* __restrict__ W2,
    const float* __restrict__ b2, const float* __restrict__ w3,
    float* __restrict__ aggr, int N)
{
    __shared__ __bf16 wt[128 * 128];          // 32 KB W2^T swizzled
    __shared__ float  w3s[128];
    __shared__ float  b2s[128];
    __shared__ __bf16 bsl[2][2][128];         // [pair-slot][rcv-of-pair] B-row
    __shared__ __bf16 hd[2][2][16 * 136];     // [pair-slot][buf] padded h-tile
    for (int idx = threadIdx.x; idx < 128 * 128; idx += 256) {
        int j = idx & 127, k = idx >> 7;
        wt[(j << 7) + ((((k >> 3) ^ (j & 7))) << 3) + (k & 7)] = (__bf16)W2[(k << 7) + j];
    }
    for (int i = threadIdx.x; i < 128; i += 256) { w3s[i] = w3[i]; b2s[i] = b2[i]; }
    __syncthreads();

    const int lane = threadIdx.x & 63;
    const int row  = lane & 15;
    const int kq   = lane >> 4;
    const int wid  = threadIdx.x >> 6;
    const int ps   = wid >> 1;
    const int hf   = wid & 1;
    const int nquad = (N + 3) >> 2;

    for (int Q = blockIdx.x; Q < nquad; Q += gridDim.x) {
        const int r0 = 4 * Q + 2 * ps;
        const int r1 = r0 + 1;
        const bool v0 = (r0 < N), v1 = (r1 < N);
        const int w0   = v0 ? offs[r0]   : 0;
        const int deg0 = v0 ? counts[r0] : 0;
        const int deg1 = v1 ? counts[r1] : 0;
        const int degsum = deg0 + deg1;
        const int o0  = 4 * Q + 2 * (ps ^ 1);
        const int od0 = (o0 < N)     ? counts[o0]     : 0;
        const int od1 = (o0 + 1 < N) ? counts[o0 + 1] : 0;
        const int osum = od0 + od1;
        const int msum = degsum > osum ? degsum : osum;
        const int ntb  = (msum + 15) >> 4;

        if (hf == 0 && lane < 32) {
            const int which = lane >> 4;
            const int rr = r0 + which;
            if (rr < N)
                *(bf16x8*)(&bsl[ps][which][(lane & 15) * 8]) =
                    *(const bf16x8*)(AB + (size_t)rr * 256 + 128 + (lane & 15) * 8);
        }

        float ca0[4] = {0, 0, 0, 0};
        float ca1[4] = {0, 0, 0, 0};

        float d_c = 0.0f; int rs_c = 0;
        bf16x8 a_c0 = {}, a_c1 = {};
        if (ntb > 0) {
            const int cl = (degsum > 0) ? ((row < degsum) ? row : degsum - 1) : 0;
            const int gi = (degsum > 0) ? w0 + cl : 0;
            const int s0 = csr_s[gi];
            d_c  = dist[gi];
            rs_c = (degsum > 0 && cl >= deg0) ? 1 : 0;
            const int kb0 = hf * 8 + kq * 2;
            a_c0 = *(const bf16x8*)(AB + (size_t)s0 * 256 + kb0 * 8);
            a_c1 = *(const bf16x8*)(AB + (size_t)s0 * 256 + (kb0 + 1) * 8);
        }
        __syncthreads();                       // bsl ready; prev Q done

        for (int tile = 0; tile < ntb; ++tile) {
            __bf16* hbuf = &hd[ps][tile & 1][0];

            int s_n = 0; float d_n = 0.0f; int rs_n = 0;
            const bool more = (tile + 1 < ntb);
            if (more) {
                const int el2 = (tile + 1) * 16 + row;
                const int cl2 = (degsum > 0) ? ((el2 < degsum) ? el2 : degsum - 1) : 0;
                const int gi2 = (degsum > 0) ? w0 + cl2 : 0;
                s_n  = csr_s[gi2];
                d_n  = dist[gi2];
                rs_n = (degsum > 0 && cl2 >= deg0) ? 1 : 0;
            }

            // ---- phase 1: my k-half of the first layer (prefetched A) -----
            {
                const int kb0 = hf * 8 + kq * 2;
#pragma unroll
                for (int i = 0; i < 2; ++i) {
                    const int kb = kb0 + i;
                    const int k0 = kb * 8;
                    bf16x8 a  = (i == 0) ? a_c0 : a_c1;
                    bf16x8 bb = *(const bf16x8*)(&bsl[ps][rs_c][k0]);
                    float4 w0f = *(const float4*)(w3s + k0);
                    float4 w1f = *(const float4*)(w3s + k0 + 4);
                    bf16x8 af;
                    af[0] = (__bf16)silu_f((float)a[0] + (float)bb[0] + d_c * w0f.x);
                    af[1] = (__bf16)silu_f((float)a[1] + (float)bb[1] + d_c * w0f.y);
                    af[2] = (__bf16)silu_f((float)a[2] + (float)bb[2] + d_c * w0f.z);
                    af[3] = (__bf16)silu_f((float)a[3] + (float)bb[3] + d_c * w0f.w);
                    af[4] = (__bf16)silu_f((float)a[4] + (float)bb[4] + d_c * w1f.x);
                    af[5] = (__bf16)silu_f((float)a[5] + (float)bb[5] + d_c * w1f.y);
                    af[6] = (__bf16)silu_f((float)a[6] + (float)bb[6] + d_c * w1f.z);
                    af[7] = (__bf16)silu_f((float)a[7] + (float)bb[7] + d_c * w1f.w);
                    *(bf16x8*)(hbuf + row * 136 + kb * 8) = af;
                }
            }

            if (more) {
                const int kb0 = hf * 8 + kq * 2;
                a_c0 = *(const bf16x8*)(AB + (size_t)s_n * 256 + kb0 * 8);
                a_c1 = *(const bf16x8*)(AB + (size_t)s_n * 256 + (kb0 + 1) * 8);
            }
            __syncthreads();                   // h-tile complete

            // ---- phase 2: my column half over the full-k h-tile -----------
            f32x4 acc[4] = {};
#pragma unroll
            for (int c = 0; c < 4; ++c) {
                const int kb2 = c * 4 + kq;
                bf16x8 af = *(const bf16x8*)(hbuf + row * 136 + kb2 * 8);
#pragma unroll
                for (int t4 = 0; t4 < 4; ++t4) {
                    const int j  = (hf * 4 + t4) * 16 + row;
                    const int jb = j & 7;
                    bf16x8 b = *(const bf16x8*)(wt + (j << 7) + ((kb2 ^ jb) << 3));
                    acc[t4] = MFMA16(af, b, acc[t4], 0, 0, 0);
                }
            }
#pragma unroll
            for (int t4 = 0; t4 < 4; ++t4) {
                const float bb = b2s[(hf * 4 + t4) * 16 + row];
#pragma unroll
                for (int q = 0; q < 4; ++q) {
                    const int er = tile * 16 + kq * 4 + q;   // combined window
                    if (er < degsum) {
                        float v = silu_f(acc[t4][q] + bb);
                        if (er < deg0) ca0[t4] += v; else ca1[t4] += v;
                    }
                }
            }

            d_c = d_n; rs_c = rs_n;
        }

#pragma unroll
        for (int t4 = 0; t4 < 4; ++t4) {
            float u0 = ca0[t4], u1 = ca1[t4];
            u0 += __shfl_xor(u0, 16, 64); u0 += __shfl_xor(u0, 32, 64);
            u1 += __shfl_xor(u1, 16, 64); u1 += __shfl_xor(u1, 32, 64);
            ca0[t4] = u0; ca1[t4] = u1;
        }
        if (kq == 0) {
#pragma unroll
            for (int t4 = 0; t4 < 4; ++t4) {
                if (v0) aggr[(size_t)r0 * 128 + (hf * 4 + t4) * 16 + row] = ca0[t4];
                if (v1) aggr[(size_t)r1 * 128 + (hf * 4 + t4) * 16 + row] = ca1[t4];
            }
        }
    }
}

// -------- phase 3: u = silu(x@U1a + aggr@U1b + c1), bf16, IN PLACE over aggr
__global__ __launch_bounds__(256) void k_node2(
    const float* __restrict__ x, const float* __restrict__ aggr,
    const float* __restrict__ U1, const float* __restrict__ c1,
    __bf16* __restrict__ u, int N, int ngroups)
{
    __shared__ __bf16 wt[128 * 256];
    for (int idx = threadIdx.x; idx < 128 * 256; idx += 256) {
        int j = idx & 127, k = idx >> 7;
        wt[(j << 8) + ((((k >> 3) ^ (j & 7))) << 3) + (k & 7)] = (__bf16)U1[(k << 7) + j];
    }
    __syncthreads();

    const int lane = threadIdx.x & 63;
    const int row  = lane & 15;
    const int kq   = lane >> 4;

    for (int g = blockIdx.x; g < ngroups; g += gridDim.x) {
        const int row0 = g * 64 + (threadIdx.x >> 6) * 16;
        int m = row0 + row; if (m >= N) m = N - 1;

        bf16x8 afr[8];
#pragma unroll
        for (int c = 0; c < 8; ++c) {
            const int k0 = (c & 3) * 32 + kq * 8;
            const float* src = (c < 4) ? (x + (size_t)m * 128 + k0)
                                       : (aggr + (size_t)m * 128 + k0);
            float4 a0 = *(const float4*)(src);
            float4 a1 = *(const float4*)(src + 4);
            bf16x8 af;
            af[0]=(__bf16)a0.x; af[1]=(__bf16)a0.y; af[2]=(__bf16)a0.z; af[3]=(__bf16)a0.w;
            af[4]=(__bf16)a1.x; af[5]=(__bf16)a1.y; af[6]=(__bf16)a1.z; af[7]=(__bf16)a1.w;
            afr[c] = af;
        }

        f32x4 acc[8] = {};
#pragma unroll
        for (int t = 0; t < 8; ++t) {
            const int j  = t * 16 + row;
            const int jb = j & 7;
            const __bf16* base = wt + (j << 8);
#pragma unroll
            for (int c = 0; c < 8; ++c) {
                const int kb = c * 4 + kq;
                bf16x8 b = *(const bf16x8*)(base + ((kb ^ jb) << 3));
                acc[t] = MFMA16(afr[c], b, acc[t], 0, 0, 0);
            }
        }

#pragma unroll
        for (int t = 0; t < 8; ++t) {
            const int col = t * 16 + row;
            const float cc = c1[col];
#pragma unroll
            for (int q = 0; q < 4; ++q) {
                const int gr = row0 + kq * 4 + q;
                if (gr < N) u[(size_t)gr * 256 + col] = (__bf16)silu_f(acc[t][q] + cc);
            }
        }
    }
}

// ---------------- phase 4: out = u@U2 + c2 (overwrites AB in d_out) ---------
__global__ __launch_bounds__(256) void k_node3(
    const __bf16* __restrict__ u, const float* __restrict__ U2,
    const float* __restrict__ c2, float* __restrict__ out, int N, int ngroups)
{
    __shared__ __bf16 wt[128 * 128];
    for (int idx = threadIdx.x; idx < 128 * 128; idx += 256) {
        int j = idx & 127, k = idx >> 7;
        wt[(j << 7) + ((((k >> 3) ^ (j & 7))) << 3) + (k & 7)] = (__bf16)U2[(k << 7) + j];
    }
    __syncthreads();

    const int lane = threadIdx.x & 63;
    const int row  = lane & 15;
    const int kq   = lane >> 4;

    for (int g = blockIdx.x; g < ngroups; g += gridDim.x) {
        const int row0 = g * 64 + (threadIdx.x >> 6) * 16;
        int m = row0 + row; if (m >= N) m = N - 1;

        bf16x8 afr[4];
#pragma unroll
        for (int c = 0; c < 4; ++c) {
            const int k0 = c * 32 + kq * 8;
            afr[c] = *(const bf16x8*)(u + (size_t)m * 256 + k0);
        }

        f32x4 acc[8] = {};
#pragma unroll
        for (int t = 0; t < 8; ++t) {
            const int j  = t * 16 + row;
            const int jb = j & 7;
            const __bf16* base = wt + (j << 7);
#pragma unroll
            for (int c = 0; c < 4; ++c) {
                const int kb = c * 4 + kq;
                bf16x8 b = *(const bf16x8*)(base + ((kb ^ jb) << 3));
                acc[t] = MFMA16(afr[c], b, acc[t], 0, 0, 0);
            }
        }

#pragma unroll
        for (int t = 0; t < 8; ++t) {
            const int col = t * 16 + row;
            const float cc = c2[col];
#pragma unroll
            for (int q = 0; q < 4; ++q) {
                const int gr = row0 + kq * 4 + q;
                if (gr < N) out[(size_t)gr * 128 + col] = acc[t][q] + cc;
            }
        }
    }
}

extern "C" void kernel_launch(void* const* d_in, const int* in_sizes, int n_in,
                              void* d_out, int out_size, void* d_ws, size_t ws_size,
                              hipStream_t stream) {
    (void)n_in; (void)out_size;
    const float* x   = (const float*)d_in[0];
    const float* pos = (const float*)d_in[1];
    const int*   ei  = (const int*)d_in[2];
    const float* W1  = (const float*)d_in[3];
    const float* b1  = (const float*)d_in[4];
    const float* W2  = (const float*)d_in[5];
    const float* b2  = (const float*)d_in[6];
    const float* U1  = (const float*)d_in[7];
    const float* c1  = (const float*)d_in[8];
    const float* U2  = (const float*)d_in[9];
    const float* c2  = (const float*)d_in[10];

    const int N = in_sizes[0] / 128;
    const int E = in_sizes[2] / 2;

    // ---- workspace layout (16B-aligned slabs) ----
    const size_t aggr_b = (size_t)N * 128 * sizeof(float);
    const size_t Ni_b   = (((size_t)N * 4) + 15) & ~(size_t)15;
    const size_t E_b    = (((size_t)E * 4) + 15) & ~(size_t)15;
    size_t off = 0;
    char* base = (char*)d_ws;
    float* aggr   = (float*)(base + off); off += aggr_b;
    int*   flag   = (int*)  (base + off); off += 16;
    int*   counts = (int*)  (base + off); off += Ni_b;
    int*   offs   = (int*)  (base + off); off += Ni_b;
    int*   cursor = (int*)  (base + off); off += Ni_b;
    int*   parts  = (int*)  (base + off); off += 256 * 4;
    int*   csr_s  = (int*)  (base + off); off += E_b;
    int*   csr_r  = (int*)  (base + off); off += E_b;
    float* dist   = (float*)(base + off); off += E_b;
    const size_t need_csr = off;

    __bf16* u  = (__bf16*)d_ws;        // row stride 256 elem, aliases aggr
    __bf16* AB = (__bf16*)d_out;       // N*256 bf16 == out_nbytes

    const int nblk_scan = (N + 511) / 512;
    const bool csr_ok = (ws_size >= need_csr) && (nblk_scan <= 256);
    if (ws_size < aggr_b + 16 || !csr_ok) return;

    const int ng_nodes = (N + 63) / 64;
    const int grid_n   = ng_nodes < 512 ? ng_nodes : 512;
    const int grid_E   = (E + 255) / 256;
    const int grid_Nt  = (N + 255) / 256;
    const int nquad    = (N + 3) / 4;
    const int grid_q   = nquad < 2048 ? nquad : 2048;

    k_detect<<<1, 256, 0, stream>>>(ei, flag);
    k_node1<<<grid_n, 256, 0, stream>>>(x, W1, b1, AB, N, ng_nodes);

    hipMemsetAsync(counts, 0, (size_t)N * 4, stream);
    k_hist   <<<grid_E, 256, 0, stream>>>(ei, flag, counts, E);
    k_scan1  <<<nblk_scan, 256, 0, stream>>>(counts, offs, parts, N);
    k_scan2  <<<1, 256, 0, stream>>>(parts, nblk_scan);
    k_scan3  <<<grid_Nt, 256, 0, stream>>>(offs, parts, cursor, N);
    k_scatter<<<grid_E, 256, 0, stream>>>(ei, flag, pos, cursor,
                                          csr_s, csr_r, dist, E);

    k_edge_p3<<<grid_q, 256, 0, stream>>>(AB, csr_s, dist, offs, counts,
                                          W2, b2, W1 + 256 * 128, aggr, N);

    k_node2<<<grid_n, 256, 0, stream>>>(x, aggr, U1, c1, u, N, ng_nodes);
    k_node3<<<grid_n, 256, 0, stream>>>(u, U2, c2, (float*)d_out, N, ng_nodes);
}